// Round 2
// baseline (270.553 us; speedup 1.0000x reference)
//
#include <hip/hip_runtime.h>
#include <math.h>

// out[f,i,j] = X[f,i] + Y[f,j] + x[i,j]
//   idx[k] = (k - 511.5) / (1024*sqrt(2))
//   X[f,i] = (cos(a_f) - idx[i]) * cos(a_f) * 0.5
//   Y[f,j] = (sin(a_f) - idx[j]) * sin(a_f) * 0.5
// W=1024, F=64. Output 256 MiB fp32 -> HBM-write-bound (ceiling ~6.55 TB/s
// per the harness's own 1 GiB fill @164us).
//
// v2: 4096 blocks x 256 thr; each block owns 16 rows of one filter.
//     - trig + per-thread Y-float4 computed ONCE per block, reused x16
//     - 16 streaming nontemporal dwordx4 stores per thread (out is
//       write-once -> keep it out of L2 so x stays resident)

#define W 1024
#define FCOUNT 64
#define ROWS_PER_BLOCK 16

typedef float v4f __attribute__((ext_vector_type(4)));

__global__ __launch_bounds__(256) void dir_diagram_kernel(
    const float* __restrict__ x,
    const float* __restrict__ filters,
    float* __restrict__ out)
{
    const int bid = blockIdx.x;
    const int f  = bid >> 6;                      // 64 blocks per filter
    const int i0 = (bid & 63) * ROWS_PER_BLOCK;   // first row of this block

    const float a = filters[f];                   // wave-uniform
    const float c = cosf(a);
    const float s = sinf(a);

    const float inv    = 1.0f / (1024.0f * 1.41421356237309504880f);
    const float center = 511.5f;

    const int j0 = threadIdx.x << 2;              // float4 column

    // Y[f, j0..j0+3] — same reference op order: (s - idx_j) * s * 0.5
    v4f yv;
    yv.x = (s - ((float)(j0 + 0) - center) * inv) * s * 0.5f;
    yv.y = (s - ((float)(j0 + 1) - center) * inv) * s * 0.5f;
    yv.z = (s - ((float)(j0 + 2) - center) * inv) * s * 0.5f;
    yv.w = (s - ((float)(j0 + 3) - center) * inv) * s * 0.5f;

    const size_t outbase = (size_t)f * ((size_t)W * W);

    #pragma unroll
    for (int r = 0; r < ROWS_PER_BLOCK; ++r) {
        const int i = i0 + r;
        const float idx_i = ((float)i - center) * inv;
        const float Xfi = (c - idx_i) * c * 0.5f;   // X[f,i]

        const v4f xv = *reinterpret_cast<const v4f*>(&x[i * W + j0]);

        v4f o;
        o.x = (Xfi + yv.x) + xv.x;   // matches ref: (X + Y) + x
        o.y = (Xfi + yv.y) + xv.y;
        o.z = (Xfi + yv.z) + xv.z;
        o.w = (Xfi + yv.w) + xv.w;

        __builtin_nontemporal_store(
            o, reinterpret_cast<v4f*>(&out[outbase + (size_t)i * W + j0]));
    }
}

extern "C" void kernel_launch(void* const* d_in, const int* in_sizes, int n_in,
                              void* d_out, int out_size, void* d_ws, size_t ws_size,
                              hipStream_t stream) {
    const float* x       = (const float*)d_in[0];
    const float* filters = (const float*)d_in[1];
    float* out           = (float*)d_out;

    dim3 grid(FCOUNT * (W / ROWS_PER_BLOCK));  // 64 * 64 = 4096 blocks
    dim3 block(256);                           // 256 thr * 4 = one 1024-wide row
    dir_diagram_kernel<<<grid, block, 0, stream>>>(x, filters, out);
}

// Round 7
// 264.140 us; speedup vs baseline: 1.0243x; 1.0243x over previous
//
#include <hip/hip_runtime.h>
#include <math.h>

// out[f,i,j] = X[f,i] + Y[f,j] + x[i,j]
//   idx[k] = (k - 511.5) / (1024*sqrt(2))
//   X[f,i] = (cos(a_f) - idx[i]) * cos(a_f) * 0.5
//   Y[f,j] = (sin(a_f) - idx[j]) * sin(a_f) * 0.5
// W=1024, F=64. Output 256 MiB fp32 -> HBM-write-bound (~6.5 TB/s ceiling
// per the harness's own 1 GiB fill @ ~165us).
//
// v3b (resubmit; rounds 3-6 never ran — GPU acquisition timeouts):
//      v2 minus nontemporal stores (suspected regression cause: nt bypasses
//      the L2 write-combining path that the 6.5 TB/s fill kernel uses),
//      ROWS_PER_BLOCK 16 -> 4. Trig via plain cosf/sinf (amortized per
//      block; keeps bit-accuracy variable out of the experiment).

#define W 1024
#define FCOUNT 64
#define ROWS_PER_BLOCK 4

typedef float v4f __attribute__((ext_vector_type(4)));

__global__ __launch_bounds__(256) void dir_diagram_kernel(
    const float* __restrict__ x,
    const float* __restrict__ filters,
    float* __restrict__ out)
{
    const int bid = blockIdx.x;
    const int f  = bid >> 8;                      // 256 blocks per filter
    const int i0 = (bid & 255) * ROWS_PER_BLOCK;  // first row of this block

    const float a = filters[f];                   // wave-uniform
    const float c = cosf(a);
    const float s = sinf(a);

    const float inv    = 1.0f / (1024.0f * 1.41421356237309504880f);
    const float center = 511.5f;

    const int j0 = threadIdx.x << 2;              // float4 column

    // Y[f, j0..j0+3] — reference op order: (s - idx_j) * s * 0.5
    v4f yv;
    yv.x = (s - ((float)(j0 + 0) - center) * inv) * s * 0.5f;
    yv.y = (s - ((float)(j0 + 1) - center) * inv) * s * 0.5f;
    yv.z = (s - ((float)(j0 + 2) - center) * inv) * s * 0.5f;
    yv.w = (s - ((float)(j0 + 3) - center) * inv) * s * 0.5f;

    const size_t outbase = (size_t)f * ((size_t)W * W);

    #pragma unroll
    for (int r = 0; r < ROWS_PER_BLOCK; ++r) {
        const int i = i0 + r;
        const float idx_i = ((float)i - center) * inv;
        const float Xfi = (c - idx_i) * c * 0.5f;   // X[f,i]

        const v4f xv = *reinterpret_cast<const v4f*>(&x[i * W + j0]);

        v4f o;
        o.x = (Xfi + yv.x) + xv.x;   // matches ref: (X + Y) + x
        o.y = (Xfi + yv.y) + xv.y;
        o.z = (Xfi + yv.z) + xv.z;
        o.w = (Xfi + yv.w) + xv.w;

        *reinterpret_cast<v4f*>(&out[outbase + (size_t)i * W + j0]) = o;
    }
}

extern "C" void kernel_launch(void* const* d_in, const int* in_sizes, int n_in,
                              void* d_out, int out_size, void* d_ws, size_t ws_size,
                              hipStream_t stream) {
    const float* x       = (const float*)d_in[0];
    const float* filters = (const float*)d_in[1];
    float* out           = (float*)d_out;

    dim3 grid(FCOUNT * (W / ROWS_PER_BLOCK));  // 64 * 256 = 16384 blocks
    dim3 block(256);                           // 256 thr * 4 = one 1024-wide row
    dir_diagram_kernel<<<grid, block, 0, stream>>>(x, filters, out);
}

// Round 8
// 260.458 us; speedup vs baseline: 1.0388x; 1.0141x over previous
//
#include <hip/hip_runtime.h>
#include <math.h>

// out[f,i,j] = X[f,i] + Y[f,j] + x[i,j]
//   idx[k] = (k - 511.5) / (1024*sqrt(2))
//   X[f,i] = (cos(a_f) - idx[i]) * cos(a_f) * 0.5
//   Y[f,j] = (sin(a_f) - idx[j]) * sin(a_f) * 0.5
// W=1024, F=64. Output 256 MiB fp32 -> HBM-write-bound.
//
// v4 "fill-like" discriminator: dur_us accounting says the kernel is already
// ~45-48us vs a ~43.6us write floor (272MB @ the fill's own 6.2TB/s), with
// ~215us of dur_us being fixed harness poison fills. This kernel matches the
// fill's execution shape (2048 blocks = 8/CU, long per-thread store streams,
// low VGPR for 8 waves/SIMD) to test the alternative reading (kernel ~90us):
//   - neutral result  -> roofline confirmed
//   - dur_us ~215-230 -> alternative was right and this captures the win
// Per block: one filter f, 32 consecutive rows; trig + per-thread Y float4
// computed once, reused x32. Regular (non-NT) dwordx4 stores — NT measured
// +13us in v2. #pragma unroll 4 bounds in-flight loads to keep VGPR <= 64.

#define W 1024
#define FCOUNT 64
#define ROWS_PER_BLOCK 32

typedef float v4f __attribute__((ext_vector_type(4)));

__global__ __launch_bounds__(256) void dir_diagram_kernel(
    const float* __restrict__ x,
    const float* __restrict__ filters,
    float* __restrict__ out)
{
    const int bid = blockIdx.x;
    const int f  = bid >> 5;                      // 32 blocks per filter
    const int i0 = (bid & 31) * ROWS_PER_BLOCK;   // first row of this block

    const float a = filters[f];                   // wave-uniform
    const float c = cosf(a);
    const float s = sinf(a);

    const float inv    = 1.0f / (1024.0f * 1.41421356237309504880f);
    const float center = 511.5f;

    const int j0 = threadIdx.x << 2;              // float4 column

    // Y[f, j0..j0+3] — reference op order: (s - idx_j) * s * 0.5
    v4f yv;
    yv.x = (s - ((float)(j0 + 0) - center) * inv) * s * 0.5f;
    yv.y = (s - ((float)(j0 + 1) - center) * inv) * s * 0.5f;
    yv.z = (s - ((float)(j0 + 2) - center) * inv) * s * 0.5f;
    yv.w = (s - ((float)(j0 + 3) - center) * inv) * s * 0.5f;

    const size_t outbase = (size_t)f * ((size_t)W * W);

    #pragma unroll 4
    for (int r = 0; r < ROWS_PER_BLOCK; ++r) {
        const int i = i0 + r;
        const float idx_i = ((float)i - center) * inv;
        const float Xfi = (c - idx_i) * c * 0.5f;   // X[f,i]

        const v4f xv = *reinterpret_cast<const v4f*>(&x[i * W + j0]);

        v4f o;
        o.x = (Xfi + yv.x) + xv.x;   // matches ref: (X + Y) + x
        o.y = (Xfi + yv.y) + xv.y;
        o.z = (Xfi + yv.z) + xv.z;
        o.w = (Xfi + yv.w) + xv.w;

        *reinterpret_cast<v4f*>(&out[outbase + (size_t)i * W + j0]) = o;
    }
}

extern "C" void kernel_launch(void* const* d_in, const int* in_sizes, int n_in,
                              void* d_out, int out_size, void* d_ws, size_t ws_size,
                              hipStream_t stream) {
    const float* x       = (const float*)d_in[0];
    const float* filters = (const float*)d_in[1];
    float* out           = (float*)d_out;

    dim3 grid(FCOUNT * (W / ROWS_PER_BLOCK));  // 64 * 32 = 2048 blocks (8/CU)
    dim3 block(256);                           // 256 thr * 4 = one 1024-wide row
    dir_diagram_kernel<<<grid, block, 0, stream>>>(x, filters, out);
}